// Round 8
// baseline (187.096 us; speedup 1.0000x reference)
//
#include <hip/hip_runtime.h>

#define N_NODES  100000
#define N_EDGES  3200000
#define NB       7                  // buckets
#define BSH      14
#define BN       16384              // nodes per bucket (7*16384 = 114688 >= 100000)
#define PBLK     512                // partition blocks
#define PTHR     512
#define PSLICE   6272               // 512*6272 >= E; divisible by 4
#define CAP_SB   1152               // per-(pblock,bucket) capacity (mean 896, +9 sigma)
#define SA       32                 // acc blocks per bucket
#define GA       (NB * SA)          // 224
#define ATHR     1024
#define PPB      (PBLK / SA)        // 16 partition blocks per acc block
#define RTHR     512

// ws layout (4-byte words):
//  cnt[PBLK*NB (=3584)] | pedge[PBLK*NB*CAP_SB] | p16 (u16, GA*BN)
//  | partials f32[GA*BN] | dinv[N] | xs[N] | us[N] | uself[N]

// ---- K1: read edges once, route into per-(block,bucket) compacted regions ---
__global__ __launch_bounds__(PTHR) void k_part(const int* __restrict__ src,
        const int* __restrict__ dstp, unsigned* __restrict__ cnt,
        unsigned* __restrict__ pedge) {
    __shared__ unsigned curs[NB];
    const int tid = threadIdx.x, lane = tid & 63;
    if (tid < NB) curs[tid] = 0;
    __syncthreads();
    const int e0 = blockIdx.x * PSLICE;
    const int qbeg = e0 >> 2;
    int qend = (e0 + PSLICE) >> 2;
    const int qmax = N_EDGES >> 2;
    if (qend > qmax) qend = qmax;
    const uint4* s4 = (const uint4*)src;
    const uint4* d4 = (const uint4*)dstp;
    unsigned* myped = pedge + (size_t)blockIdx.x * NB * CAP_SB;

    for (int q = qbeg + tid; q < qend; q += PTHR) {
        const uint4 sv = s4[q], dv = d4[q];
        const unsigned ss[4] = { sv.x, sv.y, sv.z, sv.w };
        const unsigned dd[4] = { dv.x, dv.y, dv.z, dv.w };
        #pragma unroll
        for (int k = 0; k < 4; ++k) {
            const unsigned b = dd[k] >> BSH;
            const unsigned w = ss[k] | ((dd[k] & (BN - 1u)) << 17);
            #pragma unroll
            for (unsigned bb = 0; bb < NB; ++bb) {
                const unsigned long long m = __ballot(b == bb);
                if (m) {
                    const int ldr = __ffsll((long long)m) - 1;
                    unsigned base = 0;
                    if (lane == ldr)
                        base = atomicAdd(&curs[bb], (unsigned)__popcll(m));
                    base = __shfl(base, ldr, 64);
                    if (b == bb) {
                        const unsigned pos =
                            (unsigned)__popcll(m & ((1ull << lane) - 1ull));
                        const unsigned slot = base + pos;
                        if (slot < CAP_SB) myped[bb * CAP_SB + slot] = w;
                    }
                }
            }
        }
    }
    __syncthreads();
    if (tid < NB) {
        unsigned c = curs[tid];
        cnt[blockIdx.x * NB + tid] = c < CAP_SB ? c : CAP_SB;
    }
}

// ---- degree accumulate from pedge -> u16 partials ---------------------------
__global__ __launch_bounds__(ATHR) void k_degacc(const unsigned* __restrict__ pedge,
        const unsigned* __restrict__ cnt, unsigned short* __restrict__ p16) {
    __shared__ unsigned facc[BN];
    const int tid = threadIdx.x;
    const int bu = blockIdx.x / SA, sub = blockIdx.x % SA;
    for (int i = tid; i < BN; i += ATHR) facc[i] = 0u;
    __syncthreads();
    #pragma unroll
    for (int r = 0; r < PPB; ++r) {
        const int pb = sub * PPB + r;
        const unsigned n = cnt[pb * NB + bu];
        const unsigned* reg = pedge + ((size_t)pb * NB + bu) * CAP_SB;
        for (unsigned j = tid; j < n; j += ATHR)
            atomicAdd(&facc[reg[j] >> 17], 1u);
    }
    __syncthreads();
    unsigned short* po = p16 + (size_t)blockIdx.x * BN;
    for (int i = tid; i < BN; i += ATHR) po[i] = (unsigned short)facc[i];
}

// ---- red1: sum u16 degree partials -> dinv, xs ------------------------------
__global__ __launch_bounds__(RTHR) void k_red1(const float* __restrict__ x,
        const unsigned short* __restrict__ p16,
        float* __restrict__ dinv, float* __restrict__ xs) {
    const int g = blockIdx.x * RTHR + threadIdx.x;
    if (g >= N_NODES) return;
    const int bu = g >> BSH, l = g & (BN - 1);
    const unsigned short* pp = p16 + (size_t)(bu * SA) * BN + l;
    unsigned run = 0;
    #pragma unroll
    for (int s = 0; s < SA; ++s) run += pp[(size_t)s * BN];
    const float di = rsqrtf((float)run + 1.f);      // + self loop
    dinv[g] = di;
    xs[g] = x[g] * di;
}

// ---- acc: scatter vals[src] into LDS bucket image ---------------------------
__global__ __launch_bounds__(ATHR) void k_acc(const unsigned* __restrict__ pedge,
        const unsigned* __restrict__ cnt, const float* __restrict__ vals,
        float* __restrict__ partials) {
    __shared__ float facc[BN];
    const int tid = threadIdx.x;
    const int bu = blockIdx.x / SA, sub = blockIdx.x % SA;
    for (int i = tid; i < BN; i += ATHR) facc[i] = 0.f;
    __syncthreads();
    #pragma unroll
    for (int r = 0; r < PPB; ++r) {
        const int pb = sub * PPB + r;
        const unsigned n = cnt[pb * NB + bu];
        const unsigned* reg = pedge + ((size_t)pb * NB + bu) * CAP_SB;
        for (unsigned j = tid; j < n; j += ATHR) {
            const unsigned w = reg[j];
            atomicAdd(&facc[w >> 17], vals[w & 0x1FFFFu]);
        }
    }
    __syncthreads();
    float* po = partials + (size_t)blockIdx.x * BN;
    for (int i = tid; i < BN; i += ATHR) po[i] = facc[i];
}

// ---- partial reduction helper -----------------------------------------------
__device__ __forceinline__ float sum_partials(const float* __restrict__ partials,
                                              int g) {
    const int bu = g >> BSH, l = g & (BN - 1);
    const float* pp = partials + (size_t)(bu * SA) * BN + l;
    float s = 0.f;
    #pragma unroll
    for (int k = 0; k < SA; ++k) s += pp[(size_t)k * BN];
    return s;
}

__global__ __launch_bounds__(RTHR) void k_red2(const float* __restrict__ x,
        const float* __restrict__ partials, const float* __restrict__ dinv,
        const float* __restrict__ W1, const float* __restrict__ b1,
        const float* __restrict__ W2, const float* __restrict__ Wl,
        float* __restrict__ us, float* __restrict__ uself) {
    const int g = blockIdx.x * RTHR + threadIdx.x;
    if (g >= N_NODES) return;
    const float sum = sum_partials(partials, g);
    const float di = dinv[g];
    const float s1 = di * sum + x[g] * di * di;
    float u = 0.f;
    #pragma unroll
    for (int c = 0; c < 16; ++c) {
        float vcc = 0.f;
        #pragma unroll
        for (int k = 0; k < 16; ++k) vcc += W2[c * 16 + k] * Wl[k];  // (W2@Wl)[c]
        u += fmaxf(W1[c] * s1 + b1[c], 0.f) * vcc;
    }
    us[g] = u * di;
    uself[g] = u * di * di;
}

__global__ __launch_bounds__(RTHR) void k_red3(const float* __restrict__ partials,
        const float* __restrict__ dinv, const float* __restrict__ uself,
        const float* __restrict__ W2, const float* __restrict__ b2,
        const float* __restrict__ Wl, const float* __restrict__ bl,
        float* __restrict__ out) {
    const int g = blockIdx.x * RTHR + threadIdx.x;
    if (g >= N_NODES) return;
    const float sum = sum_partials(partials, g);
    float vcb = bl[0];
    #pragma unroll
    for (int c = 0; c < 16; ++c) {
        float vcc = 0.f;
        #pragma unroll
        for (int k = 0; k < 16; ++k) vcc += W2[c * 16 + k] * Wl[k];
        vcb += b2[c] * vcc;
    }
    out[g] = dinv[g] * sum + uself[g] + vcb;
}

extern "C" void kernel_launch(void* const* d_in, const int* in_sizes, int n_in,
                              void* d_out, int out_size, void* d_ws, size_t ws_size,
                              hipStream_t stream) {
    const float* x  = (const float*)d_in[0];
    const int*   ei = (const int*)d_in[1];
    const float* W1 = (const float*)d_in[2];
    const float* b1 = (const float*)d_in[3];
    const float* W2 = (const float*)d_in[4];
    const float* b2 = (const float*)d_in[5];
    const float* Wl = (const float*)d_in[6];
    const float* bl = (const float*)d_in[7];
    float* out = (float*)d_out;

    const int* src  = ei;
    const int* dstp = ei + N_EDGES;

    unsigned* cnt         = (unsigned*)d_ws;                      // 3584 words
    unsigned* pedge       = cnt + 4096;
    unsigned short* p16   = (unsigned short*)(pedge + (size_t)PBLK * NB * CAP_SB);
    float*    partials    = (float*)(p16 + (size_t)GA * BN);
    float*    dinv        = partials + (size_t)GA * BN;
    float*    xs          = dinv + N_NODES;
    float*    us          = xs + N_NODES;
    float*    uself       = us + N_NODES;

    const int red_blocks = (N_NODES + RTHR - 1) / RTHR;   // 196

    k_part<<<PBLK, PTHR, 0, stream>>>(src, dstp, cnt, pedge);
    k_degacc<<<GA, ATHR, 0, stream>>>(pedge, cnt, p16);
    k_red1<<<red_blocks, RTHR, 0, stream>>>(x, p16, dinv, xs);
    k_acc<<<GA, ATHR, 0, stream>>>(pedge, cnt, xs, partials);
    k_red2<<<red_blocks, RTHR, 0, stream>>>(x, partials, dinv, W1, b1, W2, Wl, us, uself);
    k_acc<<<GA, ATHR, 0, stream>>>(pedge, cnt, us, partials);
    k_red3<<<red_blocks, RTHR, 0, stream>>>(partials, dinv, uself, W2, b2, Wl, bl, out);
}

// Round 9
// 181.414 us; speedup vs baseline: 1.0313x; 1.0313x over previous
//
#include <hip/hip_runtime.h>

#define N_NODES  100000
#define N_EDGES  3200000
#define NB       7                  // buckets
#define BSH      14
#define BN       16384              // nodes per bucket (7*16384 >= 100000)
#define PTHR     1024
#define NW       16                 // waves per partition block
#define PTILE    8192               // edges per partition tile
#define NTILES   ((N_EDGES + PTILE - 1) / PTILE)   // 391
#define CAP_B    600000             // per-bucket region capacity (mean ~457K)
#define SA       32                 // acc blocks per bucket
#define GA       (NB * SA)          // 224
#define ATHR     1024
#define RTHR     512

// ws layout (4-byte words):
//  cursor[256] | pedge[NB*CAP_B] | p16 (u16, GA*BN) | partials f32[GA*BN]
//  | dinv[N] | xs[N] | us[N] | uself[N]

// ---- K1: single-visit partition into bucket-contiguous regions --------------
__global__ __launch_bounds__(PTHR) void k_part(const int* __restrict__ src,
        const int* __restrict__ dstp, unsigned* __restrict__ cursor,
        unsigned* __restrict__ pedge) {
    __shared__ unsigned stage[PTILE];          // 32 KB
    __shared__ unsigned wcnt[NB * NW];         // bucket-major per-wave counts
    __shared__ unsigned woff[NB * NW];         // exclusive offsets
    __shared__ unsigned bstart[NB + 1];
    __shared__ unsigned gbase[NB];
    const int tid = threadIdx.x, wave = tid >> 6, lane = tid & 63;
    const int qbeg = (blockIdx.x * PTILE) >> 2;
    int qend = qbeg + (PTILE >> 2);
    if (qend > (N_EDGES >> 2)) qend = N_EDGES >> 2;

    const uint4* s4 = (const uint4*)src;
    const uint4* d4 = (const uint4*)dstp;
    unsigned pk[8], pos[8];
    int bk[8];
    unsigned rc0=0,rc1=0,rc2=0,rc3=0,rc4=0,rc5=0,rc6=0;  // wave-uniform run cnts

    #pragma unroll
    for (int k = 0; k < 2; ++k) {
        const int q = qbeg + k * PTHR + tid;
        const bool v = q < qend;
        uint4 sv = {0,0,0,0}, dv = {0,0,0,0};
        if (v) { sv = s4[q]; dv = d4[q]; }
        const unsigned ss[4] = { sv.x, sv.y, sv.z, sv.w };
        const unsigned dd[4] = { dv.x, dv.y, dv.z, dv.w };
        #pragma unroll
        for (int j = 0; j < 4; ++j) {
            const int i = k * 4 + j;
            const unsigned b = v ? (dd[j] >> BSH) : 0xFFu;
            bk[i] = v ? (int)b : -1;
            pk[i] = ss[j] | ((dd[j] & (BN - 1u)) << 17);
            unsigned p = 0;
            #pragma unroll
            for (unsigned bb = 0; bb < NB; ++bb) {
                const unsigned long long m = __ballot(b == bb);
                const unsigned tot = (unsigned)__popcll(m);
                const unsigned mb  = (unsigned)__popcll(m & ((1ull << lane) - 1ull));
                unsigned rcv = bb==0?rc0:bb==1?rc1:bb==2?rc2:bb==3?rc3:bb==4?rc4:bb==5?rc5:rc6;
                if (b == bb) p = rcv + mb;
                rcv += tot;
                if (bb==0) rc0=rcv; else if (bb==1) rc1=rcv; else if (bb==2) rc2=rcv;
                else if (bb==3) rc3=rcv; else if (bb==4) rc4=rcv; else if (bb==5) rc5=rcv;
                else rc6=rcv;
            }
            pos[i] = p;
        }
    }
    // publish per-(bucket,wave) totals
    if (lane == 0) wcnt[0 * NW + wave] = rc0;
    if (lane == 1) wcnt[1 * NW + wave] = rc1;
    if (lane == 2) wcnt[2 * NW + wave] = rc2;
    if (lane == 3) wcnt[3 * NW + wave] = rc3;
    if (lane == 4) wcnt[4 * NW + wave] = rc4;
    if (lane == 5) wcnt[5 * NW + wave] = rc5;
    if (lane == 6) wcnt[6 * NW + wave] = rc6;
    __syncthreads();

    // exclusive scan over 112 bucket-major counters (wave 0, 2 elems/lane)
    if (wave == 0) {
        const int i0 = lane * 2, i1 = i0 + 1;
        unsigned a0 = (i0 < NB * NW) ? wcnt[i0] : 0u;
        unsigned a1 = (i1 < NB * NW) ? wcnt[i1] : 0u;
        unsigned ps = a0 + a1;
        #pragma unroll
        for (int d = 1; d < 64; d <<= 1) {
            unsigned o = __shfl_up(ps, d, 64);
            if (lane >= d) ps += o;
        }
        const unsigned excl = ps - (a0 + a1);
        if (i0 < NB * NW) woff[i0] = excl;
        if (i1 < NB * NW) woff[i1] = excl + a0;
        if (lane == 63) bstart[NB] = ps;
    }
    __syncthreads();
    if (tid < NB) bstart[tid] = woff[tid * NW];
    __syncthreads();
    if (tid < NB) gbase[tid] = atomicAdd(&cursor[tid], bstart[tid + 1] - bstart[tid]);

    // stage, grouped by bucket
    #pragma unroll
    for (int i = 0; i < 8; ++i)
        if (bk[i] >= 0) stage[woff[bk[i] * NW + wave] + pos[i]] = pk[i];
    __syncthreads();

    // coalesced per-bucket copy-out
    for (int b = 0; b < NB; ++b) {
        const unsigned s0 = bstart[b];
        const unsigned nb2 = bstart[b + 1] - s0;
        const unsigned g0 = gbase[b];
        unsigned* dc = pedge + (size_t)b * CAP_B + g0;
        for (unsigned j = tid; j < nb2; j += PTHR) dc[j] = stage[s0 + j];
    }
}

// ---- K2: degree accumulate from compacted regions -> u16 partials -----------
__global__ __launch_bounds__(ATHR) void k_degacc(const unsigned* __restrict__ pedge,
        const unsigned* __restrict__ cursor, unsigned short* __restrict__ p16) {
    __shared__ unsigned facc[BN];
    const int tid = threadIdx.x;
    const int bu = blockIdx.x / SA, sub = blockIdx.x % SA;
    for (int i = tid; i < BN; i += ATHR) facc[i] = 0u;
    __syncthreads();
    const unsigned n = cursor[bu];
    const unsigned* reg = pedge + (size_t)bu * CAP_B;
    for (unsigned j = (unsigned)(sub * ATHR + tid); j < n; j += SA * ATHR)
        atomicAdd(&facc[reg[j] >> 17], 1u);
    __syncthreads();
    unsigned short* po = p16 + (size_t)blockIdx.x * BN;
    for (int i = tid; i < BN; i += ATHR) po[i] = (unsigned short)facc[i];
}

// ---- red1: sum u16 degree partials -> dinv, xs ------------------------------
__global__ __launch_bounds__(RTHR) void k_red1(const float* __restrict__ x,
        const unsigned short* __restrict__ p16,
        float* __restrict__ dinv, float* __restrict__ xs) {
    const int g = blockIdx.x * RTHR + threadIdx.x;
    if (g >= N_NODES) return;
    const int bu = g >> BSH, l = g & (BN - 1);
    const unsigned short* pp = p16 + (size_t)(bu * SA) * BN + l;
    unsigned run = 0;
    #pragma unroll
    for (int s = 0; s < SA; ++s) run += pp[(size_t)s * BN];
    const float di = rsqrtf((float)run + 1.f);      // + self loop
    dinv[g] = di;
    xs[g] = x[g] * di;
}

// ---- acc: scatter vals[src] into LDS bucket image ---------------------------
__global__ __launch_bounds__(ATHR) void k_acc(const unsigned* __restrict__ pedge,
        const unsigned* __restrict__ cursor, const float* __restrict__ vals,
        float* __restrict__ partials) {
    __shared__ float facc[BN];
    const int tid = threadIdx.x;
    const int bu = blockIdx.x / SA, sub = blockIdx.x % SA;
    for (int i = tid; i < BN; i += ATHR) facc[i] = 0.f;
    __syncthreads();
    const unsigned n = cursor[bu];
    const unsigned* reg = pedge + (size_t)bu * CAP_B;
    for (unsigned j = (unsigned)(sub * ATHR + tid); j < n; j += SA * ATHR) {
        const unsigned w = reg[j];
        atomicAdd(&facc[w >> 17], vals[w & 0x1FFFFu]);
    }
    __syncthreads();
    float* po = partials + (size_t)blockIdx.x * BN;
    for (int i = tid; i < BN; i += ATHR) po[i] = facc[i];
}

// ---- partial reduction helper -----------------------------------------------
__device__ __forceinline__ float sum_partials(const float* __restrict__ partials,
                                              int g) {
    const int bu = g >> BSH, l = g & (BN - 1);
    const float* pp = partials + (size_t)(bu * SA) * BN + l;
    float s = 0.f;
    #pragma unroll
    for (int k = 0; k < SA; ++k) s += pp[(size_t)k * BN];
    return s;
}

__global__ __launch_bounds__(RTHR) void k_red2(const float* __restrict__ x,
        const float* __restrict__ partials, const float* __restrict__ dinv,
        const float* __restrict__ W1, const float* __restrict__ b1,
        const float* __restrict__ W2, const float* __restrict__ Wl,
        float* __restrict__ us, float* __restrict__ uself) {
    const int g = blockIdx.x * RTHR + threadIdx.x;
    if (g >= N_NODES) return;
    const float sum = sum_partials(partials, g);
    const float di = dinv[g];
    const float s1 = di * sum + x[g] * di * di;
    float u = 0.f;
    #pragma unroll
    for (int c = 0; c < 16; ++c) {
        float vcc = 0.f;
        #pragma unroll
        for (int k = 0; k < 16; ++k) vcc += W2[c * 16 + k] * Wl[k];  // (W2@Wl)[c]
        u += fmaxf(W1[c] * s1 + b1[c], 0.f) * vcc;
    }
    us[g] = u * di;
    uself[g] = u * di * di;
}

__global__ __launch_bounds__(RTHR) void k_red3(const float* __restrict__ partials,
        const float* __restrict__ dinv, const float* __restrict__ uself,
        const float* __restrict__ W2, const float* __restrict__ b2,
        const float* __restrict__ Wl, const float* __restrict__ bl,
        float* __restrict__ out) {
    const int g = blockIdx.x * RTHR + threadIdx.x;
    if (g >= N_NODES) return;
    const float sum = sum_partials(partials, g);
    float vcb = bl[0];
    #pragma unroll
    for (int c = 0; c < 16; ++c) {
        float vcc = 0.f;
        #pragma unroll
        for (int k = 0; k < 16; ++k) vcc += W2[c * 16 + k] * Wl[k];
        vcb += b2[c] * vcc;
    }
    out[g] = dinv[g] * sum + uself[g] + vcb;
}

extern "C" void kernel_launch(void* const* d_in, const int* in_sizes, int n_in,
                              void* d_out, int out_size, void* d_ws, size_t ws_size,
                              hipStream_t stream) {
    const float* x  = (const float*)d_in[0];
    const int*   ei = (const int*)d_in[1];
    const float* W1 = (const float*)d_in[2];
    const float* b1 = (const float*)d_in[3];
    const float* W2 = (const float*)d_in[4];
    const float* b2 = (const float*)d_in[5];
    const float* Wl = (const float*)d_in[6];
    const float* bl = (const float*)d_in[7];
    float* out = (float*)d_out;

    const int* src  = ei;
    const int* dstp = ei + N_EDGES;

    unsigned* cursor      = (unsigned*)d_ws;                  // 256 words
    unsigned* pedge       = cursor + 256;
    unsigned short* p16   = (unsigned short*)(pedge + (size_t)NB * CAP_B);
    float*    partials    = (float*)(p16 + (size_t)GA * BN);
    float*    dinv        = partials + (size_t)GA * BN;
    float*    xs          = dinv + N_NODES;
    float*    us          = xs + N_NODES;
    float*    uself       = us + N_NODES;

    hipMemsetAsync(d_ws, 0, 64, stream);   // zero bucket cursors

    const int red_blocks = (N_NODES + RTHR - 1) / RTHR;   // 196

    k_part<<<NTILES, PTHR, 0, stream>>>(src, dstp, cursor, pedge);
    k_degacc<<<GA, ATHR, 0, stream>>>(pedge, cursor, p16);
    k_red1<<<red_blocks, RTHR, 0, stream>>>(x, p16, dinv, xs);
    k_acc<<<GA, ATHR, 0, stream>>>(pedge, cursor, xs, partials);
    k_red2<<<red_blocks, RTHR, 0, stream>>>(x, partials, dinv, W1, b1, W2, Wl, us, uself);
    k_acc<<<GA, ATHR, 0, stream>>>(pedge, cursor, us, partials);
    k_red3<<<red_blocks, RTHR, 0, stream>>>(partials, dinv, uself, W2, b2, Wl, bl, out);
}